// Round 4
// baseline (3931.447 us; speedup 1.0000x reference)
//
#include <hip/hip_runtime.h>
#include <hip/hip_bf16.h>
#include <stdint.h>

// ---------------------------------------------------------------------------
// Pipeline:
//  K1 build_bpk : W_bl1 [97,194,194] f32 -> Bpk fp16, MFMA b-frag layout
//                 [i=194][ks=7][t=7][lane=64][m=8] (j pad 194->224, k pad
//                 97->112).
//  K2 proj      : proj = n @ W_bl[0]  [65536,97] f32.
//  K3 score     : s = dot(proj[dst], e); atomicMax segment max.
//  K4 accum     : ex = exp(s-max); atomicAdd denom + numerator rel[dst].
//  K5 dinv      : denom -> reciprocal (0 for empty segments).
//  K6 classify/setup/scatter: bucket edges by (s-class, d-class) from
//                 dinv==0 flags: class full/inter-only/intra-only/zero.
//                 zero-s or zero-d -> skip bucket (gate = bias exactly).
//  K7 skip      : out = e*(1+sigmoid(bias)) for skip-bucket edges.
//  K8 gate_t<KS0,NKS>: per 128-edge chunk (desc-driven), stage s rows fp16 in
//                 LDS, d rows fp16 in REGISTERS; A-frag via v_pk_mul_f16;
//                 mfma_f32_16x16x32_f16, M=32/wave (2 A-tiles per B-frag);
//                 i-loop restricted to s-class range, ks-range to d-class.
//
// ws layout (bytes):
//  region A @ 0        52,428,800   proj f32 first, then rel [N,200] f32
//  Bpk     @ 52428800   9,736,192
//  idxbuf  @ 62164992     262,144   (s_buf during score/accum, then bucket idx)
//  smax    @ 62427136     524,288
//  denom   @ 62951424     524,288
//  meta    @ 63475712         256   u32[64]: cnt[10],cur@16,base@32,descn@48,estart@52
//  desc    @ 63475968      24,960   uint4[3*520]
// ---------------------------------------------------------------------------

typedef __attribute__((ext_vector_type(8))) short short8;
typedef __attribute__((ext_vector_type(4))) float f32x4;
typedef _Float16 half8 __attribute__((ext_vector_type(8)));

#define NN 65536
#define NE1 32768
#define NEG 65536
#define DC 768
#define DR 97
#define DR2 194
#define RELSTR 200
#define KI 194
#define KS 7
#define NT 7
#define EPB 128        // edges per gate block (4 waves x 32)
#define NDESC 520

#define OFF_REL   0ull
#define OFF_BPK   52428800ull
#define OFF_IDX   62164992ull
#define OFF_SMAX  62427136ull
#define OFF_DEN   62951424ull
#define OFF_META  63475712ull
#define OFF_DESC  63475968ull

static __device__ __forceinline__ unsigned fkey(float f) {
    unsigned b = __float_as_uint(f);
    return (b & 0x80000000u) ? ~b : (b | 0x80000000u);
}
static __device__ __forceinline__ float funkey(unsigned k) {
    return __uint_as_float((k & 0x80000000u) ? (k & 0x7fffffffu) : ~k);
}
static __device__ __forceinline__ unsigned pk2(_Float16 a, _Float16 b) {
    union { _Float16 h[2]; unsigned u; } x;
    x.h[0] = a; x.h[1] = b;
    return x.u;
}
static __device__ __forceinline__ int nstate(bool zi, bool zx) {
    // 0 = both halves nonzero, 1 = inter only, 2 = intra only, 3 = both zero
    return zi ? (zx ? 3 : 2) : (zx ? 1 : 0);
}

// ---------------- K1: W_bl1 -> Bpk (b-frag-packed fp16) --------------------
__global__ void build_bpk(const float* __restrict__ W, half8* __restrict__ Bpk) {
    int id = blockIdx.x * blockDim.x + threadIdx.x;  // ((i*7+ks)*7+t)*64 + l
    const int total = KI * KS * NT * 64;
    if (id >= total) return;
    int l = id & 63;
    int g = id >> 6;
    int t = g % NT;
    int ks = (g / NT) % KS;
    int i = g / (NT * KS);
    int kk = t * 16 + (l & 15);
    int jb = ks * 32 + (l >> 4) * 8;
    half8 pk;
#pragma unroll
    for (int m = 0; m < 8; ++m) {
        int j = jb + m;
        float f = (kk < DR && j < DR2) ? W[(size_t)kk * (DR2 * DR2) + i * DR2 + j] : 0.f;
        pk[m] = (_Float16)f;
    }
    Bpk[id] = pk;
}

// ---------------- K2: proj = n @ W_bl ---------------------------------------
__global__ void proj_kernel(const float* __restrict__ nmat, const float* __restrict__ Wb,
                            float* __restrict__ proj) {
    __shared__ float tile[32][128];
    int tid = threadIdx.x;
    int r0 = blockIdx.x * 32;
    float acc[32];
#pragma unroll
    for (int j = 0; j < 32; ++j) acc[j] = 0.f;
    for (int i0 = 0; i0 < DC; i0 += 128) {
#pragma unroll
        for (int q = 0; q < 32; ++q)
            tile[q][tid] = nmat[(size_t)(r0 + q) * DC + i0 + tid];
        __syncthreads();
        if (tid < DR) {
            const float* wp = Wb + (size_t)i0 * DR + tid;
            for (int ii = 0; ii < 128; ++ii) {
                float w = wp[(size_t)ii * DR];
#pragma unroll
                for (int j = 0; j < 32; ++j) acc[j] += tile[j][ii] * w;
            }
        }
        __syncthreads();
    }
    if (tid < DR) {
#pragma unroll
        for (int j = 0; j < 32; ++j) proj[(size_t)(r0 + j) * DR + tid] = acc[j];
    }
}

// ---------------- K3: per-edge score + segment max --------------------------
__global__ void score_kernel(const float* __restrict__ proj,
                             const float* __restrict__ e_inter, const float* __restrict__ e_intra,
                             const int* __restrict__ dst_inter, const int* __restrict__ dst_intra,
                             float* __restrict__ s_buf, unsigned* __restrict__ smax_key) {
    int wid = (blockIdx.x * blockDim.x + threadIdx.x) >> 6;
    int lane = threadIdx.x & 63;
    if (wid >= NEG) return;
    int et = wid >> 15, le = wid & (NE1 - 1);
    const float* e = (et ? e_intra : e_inter) + (size_t)le * DR;
    int dst = (et ? dst_intra : dst_inter)[le];
    const float* pr = proj + (size_t)dst * DR;
    float p = pr[lane] * e[lane];
    if (lane < DR - 64) p += pr[lane + 64] * e[lane + 64];
#pragma unroll
    for (int off = 32; off > 0; off >>= 1) p += __shfl_down(p, off);
    if (lane == 0) {
        s_buf[wid] = p;
        atomicMax(&smax_key[et * NN + dst], fkey(p));
    }
}

// ---------------- K4: exp + segment sums ------------------------------------
__global__ void accum_kernel(const float* __restrict__ s_buf,
                             const float* __restrict__ e_inter, const float* __restrict__ e_intra,
                             const int* __restrict__ dst_inter, const int* __restrict__ dst_intra,
                             const unsigned* __restrict__ smax_key,
                             float* __restrict__ denom, float* __restrict__ rel) {
    int wid = (blockIdx.x * blockDim.x + threadIdx.x) >> 6;
    int lane = threadIdx.x & 63;
    if (wid >= NEG) return;
    int et = wid >> 15, le = wid & (NE1 - 1);
    const float* e = (et ? e_intra : e_inter) + (size_t)le * DR;
    int dst = (et ? dst_intra : dst_inter)[le];
    float s = s_buf[wid];
    float mx = funkey(smax_key[et * NN + dst]);
    float ex = __expf(s - mx);
    if (lane == 0) atomicAdd(&denom[et * NN + dst], ex);
    float* rrow = rel + (size_t)dst * RELSTR + et * DR;
    atomicAdd(&rrow[lane], e[lane] * ex);
    if (lane < DR - 64) atomicAdd(&rrow[lane + 64], e[lane + 64] * ex);
}

// ---------------- K5: denom -> 1/denom (0 if empty) -------------------------
__global__ void dinv_kernel(float* __restrict__ denom) {
    int i = blockIdx.x * blockDim.x + threadIdx.x;
    if (i < 2 * NN) {
        float d = denom[i];
        denom[i] = (d > 0.f) ? (1.f / d) : 0.f;
    }
}

// ---------------- K6a: classify (count) -------------------------------------
__global__ void classify_kernel(const float* __restrict__ dinv,
                                const int* __restrict__ src_inter, const int* __restrict__ dst_inter,
                                const int* __restrict__ src_intra, const int* __restrict__ dst_intra,
                                unsigned* __restrict__ meta) {
    int gid = blockIdx.x * blockDim.x + threadIdx.x;
    if (gid >= NEG) return;
    int et = gid >> 15, le = gid & (NE1 - 1);
    int sn = (et ? src_intra : src_inter)[le];
    int dn = (et ? dst_intra : dst_inter)[le];
    int ss = nstate(dinv[sn] == 0.f, dinv[NN + sn] == 0.f);
    int ds = nstate(dinv[dn] == 0.f, dinv[NN + dn] == 0.f);
    int b = (ss == 3 || ds == 3) ? 9 : ss * 3 + ds;
    atomicAdd(&meta[b], 1u);
}

// ---------------- K6b: setup1 (bases, cursors, desc prefix) -----------------
__global__ void setup1_kernel(unsigned* __restrict__ meta) {
    if (threadIdx.x != 0 || blockIdx.x != 0) return;
    unsigned run = 0;
    for (int b = 0; b < 10; ++b) {
        meta[32 + b] = run;
        meta[16 + b] = run;
        run += meta[b];
    }
    meta[44] = meta[9];
    for (int dc = 0; dc < 3; ++dc) {
        unsigned e = 0;
        for (int s = 0; s < 3; ++s) {
            meta[52 + dc * 3 + s] = e;
            e += (meta[s * 3 + dc] + EPB - 1) / EPB;
        }
        meta[48 + dc] = e;
    }
}

// ---------------- K6c: setup2 (fill desc) -----------------------------------
__global__ void setup2_kernel(const unsigned* __restrict__ meta, uint4* __restrict__ desc) {
    int t = blockIdx.x * blockDim.x + threadIdx.x;
    if (t >= 3 * NDESC) return;
    int dc = t / NDESC, j = t % NDESC;
    if (j >= (int)meta[48 + dc]) return;
    int s;
    if (j < (int)meta[52 + dc * 3 + 1]) s = 0;
    else if (j < (int)meta[52 + dc * 3 + 2]) s = 1;
    else s = 2;
    int ci = j - (int)meta[52 + dc * 3 + s];
    int b = s * 3 + dc;
    int cnt = (int)meta[b];
    int cbase = (int)meta[32 + b] + ci * EPB;
    int ccnt = cnt - ci * EPB;
    if (ccnt > EPB) ccnt = EPB;
    desc[t] = make_uint4((unsigned)s, (unsigned)cbase, (unsigned)ccnt, 0);
}

// ---------------- K6d: scatter ----------------------------------------------
__global__ void scatter_kernel(const float* __restrict__ dinv,
                               const int* __restrict__ src_inter, const int* __restrict__ dst_inter,
                               const int* __restrict__ src_intra, const int* __restrict__ dst_intra,
                               unsigned* __restrict__ meta, int* __restrict__ idxbuf) {
    int gid = blockIdx.x * blockDim.x + threadIdx.x;
    if (gid >= NEG) return;
    int et = gid >> 15, le = gid & (NE1 - 1);
    int sn = (et ? src_intra : src_inter)[le];
    int dn = (et ? dst_intra : dst_inter)[le];
    int ss = nstate(dinv[sn] == 0.f, dinv[NN + sn] == 0.f);
    int ds = nstate(dinv[dn] == 0.f, dinv[NN + dn] == 0.f);
    int b = (ss == 3 || ds == 3) ? 9 : ss * 3 + ds;
    unsigned pos = atomicAdd(&meta[16 + b], 1u);
    idxbuf[pos] = gid;
}

// ---------------- K7: skip-class edges: gate = bias -------------------------
__global__ void skip_kernel(const unsigned* __restrict__ meta, const int* __restrict__ idxbuf,
                            const float* __restrict__ e_inter, const float* __restrict__ e_intra,
                            const float* __restrict__ bias, float* __restrict__ out) {
    int n9 = (int)meta[9];
    int base9 = (int)meta[41];
    int k = threadIdx.x;
    float g = 0.f;
    if (k < DR) {
        float b = bias[k];
        g = 1.f + 1.f / (1.f + __expf(-b));
    }
    for (int q = blockIdx.x; q < n9; q += gridDim.x) {
        int gid = idxbuf[base9 + q];
        int et = gid >> 15, le = gid & (NE1 - 1);
        const float* e = (et ? e_intra : e_inter) + (size_t)le * DR;
        if (k < DR) out[(size_t)gid * DR + k] = e[k] * g;
    }
}

// ---------------- K8: bilinear gate via fp16 MFMA, class-restricted ---------
template <int KS0, int NKS>
__launch_bounds__(256, 2)
__global__ void gate_t(const float* __restrict__ rel, const float* __restrict__ dinv,
                       const half8* __restrict__ Bpk, const float* __restrict__ bias,
                       const int* __restrict__ src_inter, const int* __restrict__ dst_inter,
                       const int* __restrict__ src_intra, const int* __restrict__ dst_intra,
                       const float* __restrict__ e_inter, const float* __restrict__ e_intra,
                       const int* __restrict__ idxbuf, const unsigned* __restrict__ meta,
                       const uint4* __restrict__ desc, int dc, float* __restrict__ out) {
    if (blockIdx.x >= meta[48 + dc]) return;
    uint4 de = desc[dc * NDESC + blockIdx.x];
    int sclass = (int)de.x;
    int cbase = (int)de.y;
    int ccnt = (int)de.z;
    int i0 = (sclass == 2) ? DR : 0;
    int iEnd = i0 + ((sclass == 0) ? DR2 : DR);

    __shared__ _Float16 s_lds[EPB][200];   // 51,200 B
    int tid = threadIdx.x;                 // 256

    // ---- stage s rows (rel[src] * dinv -> fp16) ----
    {
        int r = tid >> 1;                  // 0..127
        int h = tid & 1;
        int rc = cbase + ((r < ccnt) ? r : (ccnt - 1));
        int gid = idxbuf[rc];
        int et = gid >> 15, le = gid & (NE1 - 1);
        int sn = (et ? src_intra : src_inter)[le];
        float di0 = dinv[sn], di1 = dinv[NN + sn];
        const f32x4* rp = (const f32x4*)(rel + (size_t)sn * RELSTR + h * 100);
#pragma unroll
        for (int q = 0; q < 25; ++q) {
            f32x4 v = rp[q];
            int c = h * 100 + q * 4;
            _Float16 h0 = (_Float16)(v[0] * ((c + 0 < DR) ? di0 : di1));
            _Float16 h1 = (_Float16)(v[1] * ((c + 1 < DR) ? di0 : di1));
            _Float16 h2 = (_Float16)(v[2] * ((c + 2 < DR) ? di0 : di1));
            _Float16 h3 = (_Float16)(v[3] * ((c + 3 < DR) ? di0 : di1));
            *(unsigned*)&s_lds[r][c] = pk2(h0, h1);
            *(unsigned*)&s_lds[r][c + 2] = pk2(h2, h3);
        }
    }

    int w = tid >> 6;
    int lane = tid & 63;
    int lk = lane >> 4;
    int erA = (w << 5) + (lane & 15);      // rows erA and erA+16

    // ---- d rows -> registers (fp16, x dinv) ----
    half8 dA[NKS], dB[NKS];
#pragma unroll
    for (int a = 0; a < 2; ++a) {
        int er = erA + a * 16;
        int rc = cbase + ((er < ccnt) ? er : (ccnt - 1));
        int gid = idxbuf[rc];
        int et = gid >> 15, le = gid & (NE1 - 1);
        int dn = (et ? dst_intra : dst_inter)[le];
        float di0 = dinv[dn], di1 = dinv[NN + dn];
#pragma unroll
        for (int ks = 0; ks < NKS; ++ks) {
            int ksa = KS0 + ks;
            int j0 = ksa * 32 + lk * 8;
            half8 hh = {0, 0, 0, 0, 0, 0, 0, 0};
            if (!(ksa == 6 && lk > 0)) {
                const f32x4* p = (const f32x4*)(rel + (size_t)dn * RELSTR + j0);
                f32x4 v0 = p[0], v1 = p[1];
#pragma unroll
                for (int m = 0; m < 4; ++m)
                    hh[m] = (_Float16)(v0[m] * ((j0 + m < DR) ? di0 : di1));
#pragma unroll
                for (int m = 0; m < 4; ++m)
                    hh[4 + m] = (_Float16)(v1[m] * ((j0 + 4 + m < DR) ? di0 : di1));
            }
            if (a == 0) dA[ks] = hh; else dB[ks] = hh;
        }
    }
    __syncthreads();

    f32x4 accA[NT], accB[NT];
#pragma unroll
    for (int t = 0; t < NT; ++t) {
        accA[t] = (f32x4){0.f, 0.f, 0.f, 0.f};
        accB[t] = (f32x4){0.f, 0.f, 0.f, 0.f};
    }

    for (int i = i0; i < iEnd; ++i) {
        _Float16 sa = s_lds[erA][i];
        _Float16 sb = s_lds[erA + 16][i];
        half8 svA = {sa, sa, sa, sa, sa, sa, sa, sa};
        half8 svB = {sb, sb, sb, sb, sb, sb, sb, sb};
        const half8* bi = Bpk + (size_t)(i * KS + KS0) * (NT * 64) + lane;
#pragma unroll
        for (int ks = 0; ks < NKS; ++ks) {
            half8 afA = svA * dA[ks];
            half8 afB = svB * dB[ks];
#pragma unroll
            for (int t = 0; t < NT; ++t) {
                half8 bv = bi[(ks * NT + t) * 64];
                accA[t] = __builtin_amdgcn_mfma_f32_16x16x32_f16(afA, bv, accA[t], 0, 0, 0);
                accB[t] = __builtin_amdgcn_mfma_f32_16x16x32_f16(afB, bv, accB[t], 0, 0, 0);
            }
        }
    }

    // ---- epilogue: bias + sigmoid gate, scatter out = e*(1+sigmoid) ----
#pragma unroll
    for (int a = 0; a < 2; ++a) {
#pragma unroll
        for (int r = 0; r < 4; ++r) {
            int er = (w << 5) + a * 16 + lk * 4 + r;
            if (er < ccnt) {
                int gid = idxbuf[cbase + er];
                int et = gid >> 15, le = gid & (NE1 - 1);
                const float* e = (et ? e_intra : e_inter) + (size_t)le * DR;
                float* o = out + (size_t)gid * DR;
#pragma unroll
                for (int t = 0; t < NT; ++t) {
                    int k = t * 16 + (lane & 15);
                    if (k < DR) {
                        f32x4 av = (a == 0) ? accA[t] : accB[t];
                        float g = av[r] + bias[k];
                        float sg = 1.f / (1.f + __expf(-g));
                        o[k] = e[k] * (1.f + sg);
                    }
                }
            }
        }
    }
}

// ---------------------------------------------------------------------------
extern "C" void kernel_launch(void* const* d_in, const int* in_sizes, int n_in,
                              void* d_out, int out_size, void* d_ws, size_t ws_size,
                              hipStream_t stream) {
    (void)in_sizes; (void)n_in; (void)out_size; (void)ws_size;
    const float* nmat     = (const float*)d_in[0];
    const float* e_inter  = (const float*)d_in[1];
    const float* e_intra  = (const float*)d_in[2];
    const float* W_bl     = (const float*)d_in[3];
    const float* W_bl1    = (const float*)d_in[4];
    const float* b_bl1    = (const float*)d_in[5];
    const int* src_inter  = (const int*)d_in[6];
    const int* dst_inter  = (const int*)d_in[7];
    const int* src_intra  = (const int*)d_in[8];
    const int* dst_intra  = (const int*)d_in[9];
    float* out = (float*)d_out;

    char* ws = (char*)d_ws;
    float* regA     = (float*)(ws + OFF_REL);
    half8* Bpk      = (half8*)(ws + OFF_BPK);
    int* idxbuf     = (int*)(ws + OFF_IDX);      // s_buf first, idxbuf later
    float* s_buf    = (float*)(ws + OFF_IDX);
    unsigned* smax  = (unsigned*)(ws + OFF_SMAX);
    float* denom    = (float*)(ws + OFF_DEN);
    unsigned* meta  = (unsigned*)(ws + OFF_META);
    uint4* desc     = (uint4*)(ws + OFF_DESC);

    hipMemsetAsync(smax, 0, 524288, stream);
    hipMemsetAsync(denom, 0, 524288, stream);
    hipMemsetAsync(meta, 0, 256, stream);

    build_bpk<<<(KI * KS * NT * 64 + 255) / 256, 256, 0, stream>>>(W_bl1, Bpk);
    proj_kernel<<<NN / 32, 128, 0, stream>>>(nmat, W_bl, regA);
    score_kernel<<<NEG / 4, 256, 0, stream>>>(regA, e_inter, e_intra, dst_inter, dst_intra,
                                              s_buf, smax);
    hipMemsetAsync(regA, 0, 52428800, stream);   // proj dead; regA becomes rel
    accum_kernel<<<NEG / 4, 256, 0, stream>>>(s_buf, e_inter, e_intra, dst_inter, dst_intra,
                                              smax, denom, regA);
    dinv_kernel<<<512, 256, 0, stream>>>(denom);
    classify_kernel<<<NEG / 256, 256, 0, stream>>>(denom, src_inter, dst_inter,
                                                   src_intra, dst_intra, meta);
    setup1_kernel<<<1, 64, 0, stream>>>(meta);
    setup2_kernel<<<(3 * NDESC + 255) / 256, 256, 0, stream>>>(meta, desc);
    scatter_kernel<<<NEG / 256, 256, 0, stream>>>(denom, src_inter, dst_inter,
                                                  src_intra, dst_intra, meta, idxbuf);
    skip_kernel<<<2048, 128, 0, stream>>>(meta, idxbuf, e_inter, e_intra, b_bl1, out);
    gate_t<0, 7><<<NDESC, 256, 0, stream>>>(regA, denom, Bpk, b_bl1,
                                            src_inter, dst_inter, src_intra, dst_intra,
                                            e_inter, e_intra, idxbuf, meta, desc, 0, out);
    gate_t<0, 4><<<NDESC, 256, 0, stream>>>(regA, denom, Bpk, b_bl1,
                                            src_inter, dst_inter, src_intra, dst_intra,
                                            e_inter, e_intra, idxbuf, meta, desc, 1, out);
    gate_t<3, 4><<<NDESC, 256, 0, stream>>>(regA, denom, Bpk, b_bl1,
                                            src_inter, dst_inter, src_intra, dst_intra,
                                            e_inter, e_intra, idxbuf, meta, desc, 2, out);
}

// Round 5
// 1818.085 us; speedup vs baseline: 2.1624x; 2.1624x over previous
//
#include <hip/hip_runtime.h>
#include <hip/hip_bf16.h>
#include <stdint.h>

// ---------------------------------------------------------------------------
// Pipeline:
//  K1 build_bpk : W_bl1 [97,194,194] f32 -> Bpk fp16, MFMA b-frag layout
//                 [i=194][ks=7][t=7][lane=64][m=8] (j pad 194->224, k pad 97->112).
//  K2 proj      : proj = n @ W_bl[0]  [65536,97] f32.
//  K3 score     : s = dot(proj[dst], e); atomicMax segment max.
//  K4 accum     : ex = exp(s-max); atomicAdd denom + numerator rel[dst].
//  K5 dinv      : denom -> reciprocal (0 for empty segments).
//  K6 classify/setup/scatter: bucket edges by (s-class, d-class); skip bucket
//                 (either node all-zero) -> gate = bias exactly.
//  K7 skip      : out = e*(1+sigmoid(bias)) for skip-bucket edges.
//  K8 gate_all  : ONE kernel, desc-driven over all 9 buckets. Round-3 proven
//                 skeleton: 128 edges/block, 512 thr (8 waves, M=16/wave),
//                 s+d fp16 in LDS, acc in AGPRs, B-frags from global (L2).
//                 i-range by s-class; ks-range by d-class (core<KS0,KS1>).
//                 A-frag = v_pk_mul_f16(s_broadcast, d_vec).
//
// ws layout (bytes):
//  region A @ 0        52,428,800   proj f32 first, then rel [N,200] f32
//  Bpk     @ 52428800   9,736,192
//  idxbuf  @ 62164992     262,144   (s_buf during score/accum, then bucket idx)
//  smax    @ 62427136     524,288
//  denom   @ 62951424     524,288
//  meta    @ 63475712         256
//  desc    @ 63475968      24,960
// ---------------------------------------------------------------------------

typedef __attribute__((ext_vector_type(8))) short short8;
typedef __attribute__((ext_vector_type(4))) float f32x4;
typedef _Float16 half8 __attribute__((ext_vector_type(8)));

#define NN 65536
#define NE1 32768
#define NEG 65536
#define DC 768
#define DR 97
#define DR2 194
#define RELSTR 200
#define KI 194
#define KS 7
#define NT 7
#define EPB 128        // edges per gate block
#define SSTR 200       // s_lds row stride (halves) -> 400B rows (16B-mult)
#define DSTR 232       // d_lds row stride (halves) -> 464B rows (16B-mult)
#define NDESC_G 528    // max chunk descriptors

#define OFF_REL   0ull
#define OFF_BPK   52428800ull
#define OFF_IDX   62164992ull
#define OFF_SMAX  62427136ull
#define OFF_DEN   62951424ull
#define OFF_META  63475712ull
#define OFF_DESC  63475968ull

static __device__ __forceinline__ unsigned fkey(float f) {
    unsigned b = __float_as_uint(f);
    return (b & 0x80000000u) ? ~b : (b | 0x80000000u);
}
static __device__ __forceinline__ float funkey(unsigned k) {
    return __uint_as_float((k & 0x80000000u) ? (k & 0x7fffffffu) : ~k);
}
static __device__ __forceinline__ unsigned pk2(_Float16 a, _Float16 b) {
    union { _Float16 h[2]; unsigned u; } x;
    x.h[0] = a; x.h[1] = b;
    return x.u;
}
static __device__ __forceinline__ int nstate(bool zi, bool zx) {
    // 0 = both halves nonzero, 1 = inter only, 2 = intra only, 3 = both zero
    return zi ? (zx ? 3 : 2) : (zx ? 1 : 0);
}

// ---------------- K1: W_bl1 -> Bpk (b-frag-packed fp16) --------------------
__global__ void build_bpk(const float* __restrict__ W, half8* __restrict__ Bpk) {
    int id = blockIdx.x * blockDim.x + threadIdx.x;  // ((i*7+ks)*7+t)*64 + l
    const int total = KI * KS * NT * 64;
    if (id >= total) return;
    int l = id & 63;
    int g = id >> 6;
    int t = g % NT;
    int ks = (g / NT) % KS;
    int i = g / (NT * KS);
    int kk = t * 16 + (l & 15);
    int jb = ks * 32 + (l >> 4) * 8;
    half8 pk;
#pragma unroll
    for (int m = 0; m < 8; ++m) {
        int j = jb + m;
        float f = (kk < DR && j < DR2) ? W[(size_t)kk * (DR2 * DR2) + i * DR2 + j] : 0.f;
        pk[m] = (_Float16)f;
    }
    Bpk[id] = pk;
}

// ---------------- K2: proj = n @ W_bl ---------------------------------------
__global__ void proj_kernel(const float* __restrict__ nmat, const float* __restrict__ Wb,
                            float* __restrict__ proj) {
    __shared__ float tile[32][128];
    int tid = threadIdx.x;
    int r0 = blockIdx.x * 32;
    float acc[32];
#pragma unroll
    for (int j = 0; j < 32; ++j) acc[j] = 0.f;
    for (int i0 = 0; i0 < DC; i0 += 128) {
#pragma unroll
        for (int q = 0; q < 32; ++q)
            tile[q][tid] = nmat[(size_t)(r0 + q) * DC + i0 + tid];
        __syncthreads();
        if (tid < DR) {
            const float* wp = Wb + (size_t)i0 * DR + tid;
            for (int ii = 0; ii < 128; ++ii) {
                float w = wp[(size_t)ii * DR];
#pragma unroll
                for (int j = 0; j < 32; ++j) acc[j] += tile[j][ii] * w;
            }
        }
        __syncthreads();
    }
    if (tid < DR) {
#pragma unroll
        for (int j = 0; j < 32; ++j) proj[(size_t)(r0 + j) * DR + tid] = acc[j];
    }
}

// ---------------- K3: per-edge score + segment max --------------------------
__global__ void score_kernel(const float* __restrict__ proj,
                             const float* __restrict__ e_inter, const float* __restrict__ e_intra,
                             const int* __restrict__ dst_inter, const int* __restrict__ dst_intra,
                             float* __restrict__ s_buf, unsigned* __restrict__ smax_key) {
    int wid = (blockIdx.x * blockDim.x + threadIdx.x) >> 6;
    int lane = threadIdx.x & 63;
    if (wid >= NEG) return;
    int et = wid >> 15, le = wid & (NE1 - 1);
    const float* e = (et ? e_intra : e_inter) + (size_t)le * DR;
    int dst = (et ? dst_intra : dst_inter)[le];
    const float* pr = proj + (size_t)dst * DR;
    float p = pr[lane] * e[lane];
    if (lane < DR - 64) p += pr[lane + 64] * e[lane + 64];
#pragma unroll
    for (int off = 32; off > 0; off >>= 1) p += __shfl_down(p, off);
    if (lane == 0) {
        s_buf[wid] = p;
        atomicMax(&smax_key[et * NN + dst], fkey(p));
    }
}

// ---------------- K4: exp + segment sums ------------------------------------
__global__ void accum_kernel(const float* __restrict__ s_buf,
                             const float* __restrict__ e_inter, const float* __restrict__ e_intra,
                             const int* __restrict__ dst_inter, const int* __restrict__ dst_intra,
                             const unsigned* __restrict__ smax_key,
                             float* __restrict__ denom, float* __restrict__ rel) {
    int wid = (blockIdx.x * blockDim.x + threadIdx.x) >> 6;
    int lane = threadIdx.x & 63;
    if (wid >= NEG) return;
    int et = wid >> 15, le = wid & (NE1 - 1);
    const float* e = (et ? e_intra : e_inter) + (size_t)le * DR;
    int dst = (et ? dst_intra : dst_inter)[le];
    float s = s_buf[wid];
    float mx = funkey(smax_key[et * NN + dst]);
    float ex = __expf(s - mx);
    if (lane == 0) atomicAdd(&denom[et * NN + dst], ex);
    float* rrow = rel + (size_t)dst * RELSTR + et * DR;
    atomicAdd(&rrow[lane], e[lane] * ex);
    if (lane < DR - 64) atomicAdd(&rrow[lane + 64], e[lane + 64] * ex);
}

// ---------------- K5: denom -> 1/denom (0 if empty) -------------------------
__global__ void dinv_kernel(float* __restrict__ denom) {
    int i = blockIdx.x * blockDim.x + threadIdx.x;
    if (i < 2 * NN) {
        float d = denom[i];
        denom[i] = (d > 0.f) ? (1.f / d) : 0.f;
    }
}

// ---------------- K6a: classify (count) -------------------------------------
__global__ void classify_kernel(const float* __restrict__ dinv,
                                const int* __restrict__ src_inter, const int* __restrict__ dst_inter,
                                const int* __restrict__ src_intra, const int* __restrict__ dst_intra,
                                unsigned* __restrict__ meta) {
    int gid = blockIdx.x * blockDim.x + threadIdx.x;
    if (gid >= NEG) return;
    int et = gid >> 15, le = gid & (NE1 - 1);
    int sn = (et ? src_intra : src_inter)[le];
    int dn = (et ? dst_intra : dst_inter)[le];
    int ss = nstate(dinv[sn] == 0.f, dinv[NN + sn] == 0.f);
    int ds = nstate(dinv[dn] == 0.f, dinv[NN + dn] == 0.f);
    int b = (ss == 3 || ds == 3) ? 9 : ss * 3 + ds;
    atomicAdd(&meta[b], 1u);
}

// ---------------- K6b: setup1 (bases, cursors, chunk prefix) ----------------
__global__ void setup1_kernel(unsigned* __restrict__ meta) {
    if (threadIdx.x != 0 || blockIdx.x != 0) return;
    unsigned run = 0;
    for (int b = 0; b < 10; ++b) {
        meta[32 + b] = run;   // base
        meta[16 + b] = run;   // scatter cursor
        run += meta[b];
    }
    unsigned c = 0;
    for (int b = 0; b < 9; ++b) {
        meta[52 + b] = c;     // chunk start of bucket b
        c += (meta[b] + EPB - 1) / EPB;
    }
    meta[48] = c;             // total chunks
}

// ---------------- K6c: setup2 (fill desc) -----------------------------------
__global__ void setup2_kernel(const unsigned* __restrict__ meta, uint4* __restrict__ desc) {
    int j = blockIdx.x * blockDim.x + threadIdx.x;
    if (j >= (int)meta[48]) return;
    int b = 8;
    for (int q = 1; q < 9; ++q)
        if (j < (int)meta[52 + q]) { b = q - 1; break; }
    int ci = j - (int)meta[52 + b];
    int cnt = (int)meta[b];
    int cbase = (int)meta[32 + b] + ci * EPB;
    int ccnt = cnt - ci * EPB;
    if (ccnt > EPB) ccnt = EPB;
    desc[j] = make_uint4((unsigned)b, (unsigned)cbase, (unsigned)ccnt, 0);
}

// ---------------- K6d: scatter ----------------------------------------------
__global__ void scatter_kernel(const float* __restrict__ dinv,
                               const int* __restrict__ src_inter, const int* __restrict__ dst_inter,
                               const int* __restrict__ src_intra, const int* __restrict__ dst_intra,
                               unsigned* __restrict__ meta, int* __restrict__ idxbuf) {
    int gid = blockIdx.x * blockDim.x + threadIdx.x;
    if (gid >= NEG) return;
    int et = gid >> 15, le = gid & (NE1 - 1);
    int sn = (et ? src_intra : src_inter)[le];
    int dn = (et ? dst_intra : dst_inter)[le];
    int ss = nstate(dinv[sn] == 0.f, dinv[NN + sn] == 0.f);
    int ds = nstate(dinv[dn] == 0.f, dinv[NN + dn] == 0.f);
    int b = (ss == 3 || ds == 3) ? 9 : ss * 3 + ds;
    unsigned pos = atomicAdd(&meta[16 + b], 1u);
    idxbuf[pos] = gid;
}

// ---------------- K7: skip-class edges: gate = bias -------------------------
__global__ void skip_kernel(const unsigned* __restrict__ meta, const int* __restrict__ idxbuf,
                            const float* __restrict__ e_inter, const float* __restrict__ e_intra,
                            const float* __restrict__ bias, float* __restrict__ out) {
    int n9 = (int)meta[9];
    int base9 = (int)meta[41];
    int k = threadIdx.x;
    float g = 0.f;
    if (k < DR) {
        float b = bias[k];
        g = 1.f + 1.f / (1.f + __expf(-b));
    }
    for (int q = blockIdx.x; q < n9; q += gridDim.x) {
        int gid = idxbuf[base9 + q];
        int et = gid >> 15, le = gid & (NE1 - 1);
        const float* e = (et ? e_intra : e_inter) + (size_t)le * DR;
        if (k < DR) out[(size_t)gid * DR + k] = e[k] * g;
    }
}

// ---------------- K8 core: ks-range-specialized MFMA loop -------------------
template <int KS0, int KS1>
static __device__ __forceinline__ void gate_core(
    const _Float16 (*__restrict__ s_lds)[SSTR],
    const _Float16 (*__restrict__ d_lds)[DSTR],
    const half8* __restrict__ bl,   // Bpk + lane
    int i0, int iEnd, int er, int lk, f32x4 acc[NT])
{
    for (int i = i0; i < iEnd; ++i) {
        _Float16 sa = s_lds[er][i];
        half8 sv = {sa, sa, sa, sa, sa, sa, sa, sa};
        const half8* bi = bl + (size_t)(i * KS + KS0) * (NT * 64);
#pragma unroll
        for (int ks = 0; ks < KS1 - KS0; ++ks) {
            half8 dv = *(const half8*)&d_lds[er][(KS0 + ks) * 32 + lk * 8];
            half8 af = sv * dv;
#pragma unroll
            for (int t = 0; t < NT; ++t) {
                half8 bv = bi[(ks * NT + t) * 64];
                acc[t] = __builtin_amdgcn_mfma_f32_16x16x32_f16(af, bv, acc[t], 0, 0, 0);
            }
        }
    }
}

// ---------------- K8: unified bilinear gate ---------------------------------
__launch_bounds__(512, 1)
__global__ void gate_all(const float* __restrict__ rel, const float* __restrict__ dinv,
                         const half8* __restrict__ Bpk, const float* __restrict__ bias,
                         const int* __restrict__ src_inter, const int* __restrict__ dst_inter,
                         const int* __restrict__ src_intra, const int* __restrict__ dst_intra,
                         const float* __restrict__ e_inter, const float* __restrict__ e_intra,
                         const int* __restrict__ idxbuf, const unsigned* __restrict__ meta,
                         const uint4* __restrict__ desc, float* __restrict__ out) {
    if (blockIdx.x >= meta[48]) return;
    uint4 de = desc[blockIdx.x];
    int b = (int)de.x;
    int sclass = b / 3;
    int dc = b - sclass * 3;
    int cbase = (int)de.y;
    int ccnt = (int)de.z;
    int i0 = (sclass == 2) ? DR : 0;
    int iEnd = (sclass == 0) ? DR2 : (i0 + DR);

    __shared__ __align__(16) _Float16 s_lds[EPB][SSTR];   // 51,200 B
    __shared__ __align__(16) _Float16 d_lds[EPB][DSTR];   // 59,392 B
    int tid = threadIdx.x;                                // 512

    // ---- stage s rows (x dinv -> fp16 LDS) and d rows ----
    {
        int r = tid >> 1;                 // 0..255
        int h = tid & 1;                  // half of the row (100 f32 each)
        int edge = r & 127;
        bool isd = (r >= 128);
        int rc = cbase + ((edge < ccnt) ? edge : (ccnt - 1));
        int gid = idxbuf[rc];
        int et = gid >> 15, le = gid & (NE1 - 1);
        int node = isd ? (et ? dst_intra : dst_inter)[le]
                       : (et ? src_intra : src_inter)[le];
        float di0 = dinv[node];
        float di1 = dinv[NN + node];
        const f32x4* rp = (const f32x4*)(rel + (size_t)node * RELSTR + h * 100);
        _Float16* row = isd ? &d_lds[edge][0] : &s_lds[edge][0];
#pragma unroll
        for (int q = 0; q < 25; ++q) {
            f32x4 v = rp[q];
            int c = h * 100 + q * 4;
            _Float16 h0 = (_Float16)(v[0] * ((c + 0 < DR) ? di0 : di1));
            _Float16 h1 = (_Float16)(v[1] * ((c + 1 < DR) ? di0 : di1));
            _Float16 h2 = (_Float16)(v[2] * ((c + 2 < DR) ? di0 : di1));
            _Float16 h3 = (_Float16)(v[3] * ((c + 3 < DR) ? di0 : di1));
            *(unsigned*)&row[c] = pk2(h0, h1);
            *(unsigned*)&row[c + 2] = pk2(h2, h3);
        }
        if (isd && h) {   // zero d cols 200..223 (K padding read by ks=6)
            short8 z = (short8)(short)0;
#pragma unroll
            for (int q = 0; q < 3; ++q)
                *(short8*)&row[200 + q * 8] = z;
        }
    }
    __syncthreads();

    int w = tid >> 6;                 // wave 0..7: edges [w*16, w*16+16)
    int lane = tid & 63;
    int lk = lane >> 4;
    int er = (w << 4) + (lane & 15);

    f32x4 acc[NT];
#pragma unroll
    for (int t = 0; t < NT; ++t) acc[t] = (f32x4){0.f, 0.f, 0.f, 0.f};

    const half8* bl = Bpk + lane;
    if (dc == 0)      gate_core<0, 7>(s_lds, d_lds, bl, i0, iEnd, er, lk, acc);
    else if (dc == 1) gate_core<0, 4>(s_lds, d_lds, bl, i0, iEnd, er, lk, acc);
    else              gate_core<3, 7>(s_lds, d_lds, bl, i0, iEnd, er, lk, acc);

    // ---- epilogue: bias + sigmoid, scatter out = e*(1+sigmoid) ----
#pragma unroll
    for (int r = 0; r < 4; ++r) {
        int row = (w << 4) + lk * 4 + r;
        if (row < ccnt) {
            int gid = idxbuf[cbase + row];
            int et = gid >> 15, le = gid & (NE1 - 1);
            const float* e = (et ? e_intra : e_inter) + (size_t)le * DR;
            float* o = out + (size_t)gid * DR;
#pragma unroll
            for (int t = 0; t < NT; ++t) {
                int k = t * 16 + (lane & 15);
                if (k < DR) {
                    float g = acc[t][r] + bias[k];
                    float sg = 1.f / (1.f + __expf(-g));
                    o[k] = e[k] * (1.f + sg);
                }
            }
        }
    }
}

// ---------------------------------------------------------------------------
extern "C" void kernel_launch(void* const* d_in, const int* in_sizes, int n_in,
                              void* d_out, int out_size, void* d_ws, size_t ws_size,
                              hipStream_t stream) {
    (void)in_sizes; (void)n_in; (void)out_size; (void)ws_size;
    const float* nmat     = (const float*)d_in[0];
    const float* e_inter  = (const float*)d_in[1];
    const float* e_intra  = (const float*)d_in[2];
    const float* W_bl     = (const float*)d_in[3];
    const float* W_bl1    = (const float*)d_in[4];
    const float* b_bl1    = (const float*)d_in[5];
    const int* src_inter  = (const int*)d_in[6];
    const int* dst_inter  = (const int*)d_in[7];
    const int* src_intra  = (const int*)d_in[8];
    const int* dst_intra  = (const int*)d_in[9];
    float* out = (float*)d_out;

    char* ws = (char*)d_ws;
    float* regA     = (float*)(ws + OFF_REL);
    half8* Bpk      = (half8*)(ws + OFF_BPK);
    int* idxbuf     = (int*)(ws + OFF_IDX);      // s_buf first, idxbuf later
    float* s_buf    = (float*)(ws + OFF_IDX);
    unsigned* smax  = (unsigned*)(ws + OFF_SMAX);
    float* denom    = (float*)(ws + OFF_DEN);
    unsigned* meta  = (unsigned*)(ws + OFF_META);
    uint4* desc     = (uint4*)(ws + OFF_DESC);

    hipMemsetAsync(smax, 0, 524288, stream);
    hipMemsetAsync(denom, 0, 524288, stream);
    hipMemsetAsync(meta, 0, 256, stream);

    build_bpk<<<(KI * KS * NT * 64 + 255) / 256, 256, 0, stream>>>(W_bl1, Bpk);
    proj_kernel<<<NN / 32, 128, 0, stream>>>(nmat, W_bl, regA);
    score_kernel<<<NEG / 4, 256, 0, stream>>>(regA, e_inter, e_intra, dst_inter, dst_intra,
                                              s_buf, smax);
    hipMemsetAsync(regA, 0, 52428800, stream);   // proj dead; regA becomes rel
    accum_kernel<<<NEG / 4, 256, 0, stream>>>(s_buf, e_inter, e_intra, dst_inter, dst_intra,
                                              smax, denom, regA);
    dinv_kernel<<<512, 256, 0, stream>>>(denom);
    classify_kernel<<<NEG / 256, 256, 0, stream>>>(denom, src_inter, dst_inter,
                                                   src_intra, dst_intra, meta);
    setup1_kernel<<<1, 64, 0, stream>>>(meta);
    setup2_kernel<<<(NDESC_G + 255) / 256, 256, 0, stream>>>(meta, desc);
    scatter_kernel<<<NEG / 256, 256, 0, stream>>>(denom, src_inter, dst_inter,
                                                  src_intra, dst_intra, meta, idxbuf);
    skip_kernel<<<2048, 128, 0, stream>>>(meta, idxbuf, e_inter, e_intra, b_bl1, out);
    gate_all<<<NDESC_G, 512, 0, stream>>>(regA, denom, Bpk, b_bl1,
                                          src_inter, dst_inter, src_intra, dst_intra,
                                          e_inter, e_intra, idxbuf, meta, desc, out);
}